// Round 5
// baseline (1397.805 us; speedup 1.0000x reference)
//
#include <hip/hip_runtime.h>

namespace {
constexpr int UNITS = 2048;
constexpr int D_IN  = 96;
constexpr int BATCH = 64;
constexpr int T     = 512;
constexpr int NNZ   = 960;   // D_IN * C_IN
constexpr int C_REC = 10;
constexpr int CHUNK = 128;   // x timesteps staged in LDS per refill
constexpr int NT    = 512;   // threads per block; each thread owns 4 units

// LDS byte-offset arena
constexpr int HA = 0;          // h ping   (8 KB)
constexpr int HB = 8192;       // h pong   (8 KB)
constexpr int IA = 16384;      // input_part ping (8 KB)
constexpr int IB = 24576;      // input_part pong (8 KB)
constexpr int XO = 32768;      // x chunk (48 KB)
constexpr int LDS_BYTES = XO + CHUNK * D_IN * 4;   // 80 KB

// workspace layout for the bank-phased gather ordering
constexpr int IDXP_BYTES = 4 * C_REC * NT * 4;     // 40 slots x 512 threads x int
constexpr int PERM_BYTES = 2 * IDXP_BYTES;         // + float weights
}

typedef float f32x2 __attribute__((ext_vector_type(2)));
typedef float f32x4 __attribute__((ext_vector_type(4)));

// lgkm-only barrier: __syncthreads() would drain vmcnt(0) and stall on the
// streaming out-stores every step.
__device__ __forceinline__ void bar_lds() {
  asm volatile("s_waitcnt lgkmcnt(0)\n\ts_barrier" ::: "memory");
}

__device__ __forceinline__ float fast_tanh(float x) {
  float e = __expf(2.0f * x);
  return 1.0f - __fdividef(2.0f, e + 1.0f);
}

// ---------------------------------------------------------------------------
// Prep: per (thread, unit) sort the 10 (idx,w) entries by LDS bank (idx&31),
// then rotate by a lane-dependent phase phi so that at gather slot s the 64
// lanes of a wave read uniformly spread bank-quantiles -> per-slot max lanes
// per bank drops from ~5-6 (random) to ~3 -> conflict factor ~1.9x -> ~1.25x.
// Output layout [slot][tid] so the main kernel's hoist loads are coalesced.
// idxp holds byte offsets (idx*4).
// ---------------------------------------------------------------------------
__global__ void prep_kernel(const int* __restrict__ ridx,
                            const float* __restrict__ rvals,
                            int* __restrict__ idxp, float* __restrict__ wp) {
  const int tid  = threadIdx.x;          // 0..511, matches main kernel tid
  const int lane = tid & 63;
  const int phi  = (lane * C_REC) >> 6;  // 0..9, ~6.4 lanes per phase
  for (int lu = 0; lu < 4; ++lu) {
    const int u = tid * 4 + lu;
    int idx[C_REC]; float w[C_REC];
    for (int c = 0; c < C_REC; ++c) {
      idx[c] = ridx[u * C_REC + c];
      w[c]   = rvals[u * C_REC + c];
    }
    for (int i = 1; i < C_REC; ++i) {    // insertion sort by bank
      int ii = idx[i]; float ww = w[i]; int bi = ii & 31;
      int j = i - 1;
      while (j >= 0 && (idx[j] & 31) > bi) { idx[j+1] = idx[j]; w[j+1] = w[j]; --j; }
      idx[j+1] = ii; w[j+1] = ww;
    }
    for (int q = 0; q < C_REC; ++q) {    // bank-rank q -> slot (q - phi) mod 10
      int s = q - phi; if (s < 0) s += C_REC;
      idxp[(lu * C_REC + s) * NT + tid] = idx[q] * 4;
      wp  [(lu * C_REC + s) * NT + tid] = w[q];
    }
  }
}

// hoisted recurrent entries: 40 idx + 40 w named scalars, 4 units a/b/c/d
#define RDECL(L, lu, n)                                                        \
  const int   i##L##n = PERM ? idxp[((lu) * C_REC + (n)) * NT + tid]           \
                             : ridx[(u0 + (lu)) * C_REC + (n)] * 4;            \
  const float w##L##n = PERM ? wp[((lu) * C_REC + (n)) * NT + tid]             \
                             : rvals[(u0 + (lu)) * C_REC + (n)];
#define RDECL10(L, lu)                                                         \
  RDECL(L, lu, 0) RDECL(L, lu, 1) RDECL(L, lu, 2) RDECL(L, lu, 3)              \
  RDECL(L, lu, 4) RDECL(L, lu, 5) RDECL(L, lu, 6) RDECL(L, lu, 7)              \
  RDECL(L, lu, 8) RDECL(L, lu, 9)

#define GAT(HC, L, n)                                                          \
  s##L += *(const float*)(smem + (HC) + i##L##n) * w##L##n;
#define GAT10(HC, L)                                                           \
  GAT(HC, L, 0) GAT(HC, L, 1) GAT(HC, L, 2) GAT(HC, L, 3) GAT(HC, L, 4)        \
  GAT(HC, L, 5) GAT(HC, L, 6) GAT(HC, L, 7) GAT(HC, L, 8) GAT(HC, L, 9)

// One timestep. HC/HN = h cur/next, IR = input_part consumed (read+re-zero),
// IW = input_part being built for step t+1 (overlaps: disjoint buffers).
#define STEP(HC, HN, IR, IW, SLOT_NEXT, DO_SCATTER, TSTEP)                     \
  {                                                                            \
    if (DO_SCATTER) {                                                          \
      float xv1 = *(const float*)(smem + XO + (SLOT_NEXT) * (D_IN * 4) + krb1);\
      atomicAdd((float*)(smem + (IW) + kcb1), xv1 * kv1);                      \
      if (tid < NNZ - NT) {                                                    \
        float xv2 = *(const float*)(smem + XO + (SLOT_NEXT)*(D_IN*4) + krb2);  \
        atomicAdd((float*)(smem + (IW) + kcb2), xv2 * kv2);                    \
      }                                                                        \
    }                                                                          \
    f32x4 in4 = *(f32x4*)(smem + (IR) + tid * 16);                             \
    *(f32x4*)(smem + (IR) + tid * 16) = (f32x4){0.f, 0.f, 0.f, 0.f};           \
    float sa = in4.x + bias4.x, sb = in4.y + bias4.y;                          \
    float sc = in4.z + bias4.z, sd = in4.w + bias4.w;                          \
    GAT10(HC, a) GAT10(HC, b) GAT10(HC, c) GAT10(HC, d)                        \
    f32x4 hh = {fast_tanh(sa), fast_tanh(sb), fast_tanh(sc), fast_tanh(sd)};   \
    *(f32x4*)(smem + (HN) + tid * 16) = hh;                                    \
    __builtin_nontemporal_store(hh, outp + (size_t)(TSTEP) * (UNITS / 4));     \
    bar_lds();                                                                 \
  }

template <bool PERM>
__global__ __launch_bounds__(NT, 2) void reservoir_kernel(
    const float* __restrict__ inputs, const float* __restrict__ state0,
    const float* __restrict__ kvals,  const float* __restrict__ rvals,
    const float* __restrict__ bias,   const int* __restrict__ krows,
    const int* __restrict__ kcols,    const int* __restrict__ ridx,
    const int* __restrict__ idxp,     const float* __restrict__ wp,
    float* __restrict__ out)
{
  __shared__ __align__(16) char smem[LDS_BYTES];
  const int tid = threadIdx.x;
  const int b   = blockIdx.x;
  const int u0  = tid * 4;          // this thread owns units u0..u0+3

  // zero input_part ping+pong
  *(f32x4*)(smem + IA + tid * 16) = (f32x4){0.f, 0.f, 0.f, 0.f};
  *(f32x4*)(smem + IB + tid * 16) = (f32x4){0.f, 0.f, 0.f, 0.f};
  // stage h_0
  *(f32x4*)(smem + HA + tid * 16) = *(const f32x4*)(state0 + b * UNITS + u0);

  RDECL10(a, 0) RDECL10(b, 1) RDECL10(c, 2) RDECL10(d, 3)

  const f32x4 bias4 = *(const f32x4*)(bias + u0);

  // input-kernel COO: entries tid and tid+512 (960 total)
  int krb1 = krows[tid] * 4, kcb1 = kcols[tid] * 4;
  float kv1 = kvals[tid];
  int krb2 = 0, kcb2 = 0; float kv2 = 0.f;
  if (tid < NNZ - NT) {
    krb2 = krows[NT + tid] * 4;
    kcb2 = kcols[NT + tid] * 4;
    kv2  = kvals[NT + tid];
  }

  const float* xin  = inputs + (size_t)b * (T * D_IN);
  f32x4*       outp = (f32x4*)out + (size_t)b * (T * (UNITS / 4)) + tid;

  __syncthreads();

  for (int tb = 0; tb < T; tb += CHUNK) {
    // bulk-refill x chunk (48 KB): 6 float4 per thread
#pragma unroll
    for (int k = 0; k < 6; ++k) {
      float4 v = *(const float4*)(xin + tb * D_IN + (tid + k * NT) * 4);
      *(float4*)(smem + XO + (tid + k * NT) * 16) = v;
    }
    bar_lds();
    // prime input_part for slot 0 of this chunk (IA is zeroed)
    {
      float xv1 = *(const float*)(smem + XO + krb1);
      atomicAdd((float*)(smem + IA + kcb1), xv1 * kv1);
      if (tid < NNZ - NT) {
        float xv2 = *(const float*)(smem + XO + krb2);
        atomicAdd((float*)(smem + IA + kcb2), xv2 * kv2);
      }
    }
    bar_lds();
#pragma unroll 1
    for (int ts = 0; ts < CHUNK; ts += 2) {
      STEP(HA, HB, IA, IB, ts + 1, true,              tb + ts);
      STEP(HB, HA, IB, IA, ts + 2, (ts + 2) < CHUNK,  tb + ts + 1);
    }
  }
}

extern "C" void kernel_launch(void* const* d_in, const int* in_sizes, int n_in,
                              void* d_out, int out_size, void* d_ws, size_t ws_size,
                              hipStream_t stream) {
  const float* inputs = (const float*)d_in[0];
  const float* state0 = (const float*)d_in[1];
  const float* kvals  = (const float*)d_in[2];
  const float* rvals  = (const float*)d_in[3];
  const float* bias   = (const float*)d_in[4];
  const int*   krows  = (const int*)d_in[5];
  const int*   kcols  = (const int*)d_in[6];
  const int*   ridx   = (const int*)d_in[7];

  int*   idxp = (int*)d_ws;
  float* wp   = (float*)((char*)d_ws + IDXP_BYTES);

  if (ws_size >= (size_t)PERM_BYTES) {
    prep_kernel<<<dim3(1), dim3(NT), 0, stream>>>(ridx, rvals, idxp, wp);
    reservoir_kernel<true><<<dim3(BATCH), dim3(NT), 0, stream>>>(
        inputs, state0, kvals, rvals, bias, krows, kcols, ridx, idxp, wp,
        (float*)d_out);
  } else {
    reservoir_kernel<false><<<dim3(BATCH), dim3(NT), 0, stream>>>(
        inputs, state0, kvals, rvals, bias, krows, kcols, ridx, idxp, wp,
        (float*)d_out);
  }
}

// Round 6
// 1214.149 us; speedup vs baseline: 1.1513x; 1.1513x over previous
//
#include <hip/hip_runtime.h>

namespace {
constexpr int UNITS = 2048;
constexpr int D_IN  = 96;
constexpr int BATCH = 64;
constexpr int T     = 512;
constexpr int NNZ   = 960;   // D_IN * C_IN
constexpr int C_REC = 10;
constexpr int CHUNK = 128;   // x timesteps staged in LDS per refill
constexpr int NT    = 1024;  // threads per block; 2 units per thread (R1 structure)

// main-kernel LDS arena (bytes). h buffers hold TWO copies: copy A at
// [base, base+8K) indexed by u, copy B at [base+8K, base+16K) indexed by
// v = u ^ ((u>>5)&31)  (involution -> injective; bank(v) decorrelated from
// bank(u)). Gather entries statically pick the copy that balances banks.
constexpr int HPING = 0;
constexpr int HPONG = 16384;
constexpr int IA    = 32768;   // input_part ping (8 KB)
constexpr int IB    = 40960;   // input_part pong (8 KB)
constexpr int XO    = 49152;   // x chunk (48 KB)
constexpr int LDS_BYTES = XO + CHUNK * D_IN * 4;   // 96 KB

// workspace: scheduled gather tables, [slot][tid] coalesced
constexpr int OFFA_OFS = 0;                   // int   [10][1024]
constexpr int WA_OFS   = C_REC * NT * 4;      // float [10][1024]
constexpr int OFFB_OFS = 2 * C_REC * NT * 4;
constexpr int WB_OFS   = 3 * C_REC * NT * 4;
constexpr int WS_NEED  = 4 * C_REC * NT * 4;  // 160 KB
}

typedef float f32x2 __attribute__((ext_vector_type(2)));

// lgkm-only barrier: __syncthreads() drains vmcnt(0) -> would stall on the
// streaming out-stores every step.
__device__ __forceinline__ void bar_lds() {
  asm volatile("s_waitcnt lgkmcnt(0)\n\ts_barrier" ::: "memory");
}

__device__ __forceinline__ float fast_tanh(float x) {
  float e = __expf(2.0f * x);
  return 1.0f - __fdividef(2.0f, e + 1.0f);
}

// ---------------------------------------------------------------------------
// Prep: joint per-wave greedy bank scheduling (R5's per-lane quantile trick
// ANTI-worked: lanes sharing a phase all read the same bank quantile ->
// conflicts +27%. Assignment must be solved jointly across the 64 lanes.)
// For each of the main kernel's 16 waves and each of its 20 gather
// instruction slots (A0,B0,A1,B1,...), lanes pick (remaining entry, copy A/B)
// minimizing the slot's per-bank load — sequential across lanes, wavefront-
// parallel across (slot+lane) anti-diagonals. Two choices per entry even for
// the forced last pick -> max load ~2-3; 2-way is free.
// Emits final LDS byte-offsets (copy B offsets carry the +8192) and weights.
// ---------------------------------------------------------------------------
__global__ __launch_bounds__(1024) void prep_kernel(
    const int* __restrict__ ridx, const float* __restrict__ rvals,
    int* __restrict__ offA, float* __restrict__ wA,
    int* __restrict__ offB, float* __restrict__ wB)
{
  __shared__ unsigned short off16[UNITS][C_REC][2];  // 80 KB: both copies' offsets
  __shared__ unsigned char  hist[16][20][32];        // per (wave, slot) bank load
  __shared__ unsigned short rem[16][64][2];          // remaining-entry bitmask
  const int tid = threadIdx.x;

  for (int i = tid; i < UNITS * C_REC; i += 1024) {
    int idx = ridx[i];
    int v   = idx ^ ((idx >> 5) & 31);
    off16[i / C_REC][i % C_REC][0] = (unsigned short)(idx * 4);
    off16[i / C_REC][i % C_REC][1] = (unsigned short)(8192 + v * 4);
  }
  for (int i = tid; i < 16 * 20 * 32; i += 1024) ((unsigned char*)hist)[i] = 0;
  for (int i = tid; i < 16 * 64 * 2; i += 1024) ((unsigned short*)rem)[i] = 0x3FF;
  __syncthreads();

  const int w = tid >> 6, l = tid & 63;
  for (int step = 0; step < 20 + 63; ++step) {
    const int s = step - l;               // cell (s,l): dep (s-1,l) and (s,l-1)
    if (s >= 0 && s < 20) {
      const int usel = s & 1;             // 0 = unit A, 1 = unit B
      const int ord  = s >> 1;            // gather slot within the unit
      const int u    = 2 * (w * 64 + l) + usel;
      unsigned m = rem[w][l][usel];
      int beste = 0, bestload = 255, bestoff = 0;
#pragma unroll
      for (int e = 0; e < C_REC; ++e) {
        if (!((m >> e) & 1)) continue;
#pragma unroll
        for (int c = 0; c < 2; ++c) {
          int off = off16[u][e][c];
          int ld  = hist[w][s][(off >> 2) & 31];
          if (ld < bestload) { bestload = ld; beste = e; bestoff = off; }
        }
      }
      hist[w][s][(bestoff >> 2) & 31] = (unsigned char)(bestload + 1);
      rem[w][l][usel] = (unsigned short)(m & ~(1u << beste));
      const int tmain = w * 64 + l;
      const float wv  = rvals[u * C_REC + beste];
      if (usel == 0) { offA[ord * NT + tmain] = bestoff; wA[ord * NT + tmain] = wv; }
      else           { offB[ord * NT + tmain] = bestoff; wB[ord * NT + tmain] = wv; }
    }
    __syncthreads();
  }
}

// hoisted gather tables as named scalars
#define RDECL(n)                                                               \
  const int   oa##n = PERM ? offA[(n) * NT + tid] : ridx[u0 * C_REC + (n)] * 4;\
  const float va##n = PERM ? wA[(n) * NT + tid]   : rvals[u0 * C_REC + (n)];   \
  const int   ob##n = PERM ? offB[(n) * NT + tid]                              \
                           : ridx[(u0 + 1) * C_REC + (n)] * 4;                 \
  const float vb##n = PERM ? wB[(n) * NT + tid]                                \
                           : rvals[(u0 + 1) * C_REC + (n)];

#define GAT(HC, n)                                                             \
  s0 += *(const float*)(smem + (HC) + oa##n) * va##n;                          \
  s1 += *(const float*)(smem + (HC) + ob##n) * vb##n;

// One timestep. HC/HN = h cur/next base (each holds copies A+B), IR =
// input_part consumed (read+re-zero), IW = input_part built for step t+1.
#define STEP(HC, HN, IR, IW, SLOT_NEXT, DO_SCATTER, TSTEP)                     \
  {                                                                            \
    if ((DO_SCATTER) && tid < NNZ) {                                           \
      float xv = *(const float*)(smem + XO + (SLOT_NEXT) * (D_IN * 4) + krb);  \
      atomicAdd((float*)(smem + (IW) + kcb), xv * kv);                         \
    }                                                                          \
    f32x2 in2 = *(f32x2*)(smem + (IR) + tid * 8);                              \
    *(f32x2*)(smem + (IR) + tid * 8) = (f32x2){0.f, 0.f};                      \
    float s0 = in2.x + bias2.x;                                                \
    float s1 = in2.y + bias2.y;                                                \
    GAT(HC, 0) GAT(HC, 1) GAT(HC, 2) GAT(HC, 3) GAT(HC, 4)                     \
    GAT(HC, 5) GAT(HC, 6) GAT(HC, 7) GAT(HC, 8) GAT(HC, 9)                     \
    f32x2 hh = {fast_tanh(s0), fast_tanh(s1)};                                 \
    *(f32x2*)(smem + (HN) + tid * 8) = hh;                                     \
    f32x2 hb2 = vswap ? (f32x2){hh.y, hh.x} : hh;                              \
    *(f32x2*)(smem + (HN) + vbyte) = hb2;                                      \
    __builtin_nontemporal_store(hh, outp + (size_t)(TSTEP) * (UNITS / 2));     \
    bar_lds();                                                                 \
  }

template <bool PERM>
__global__ __launch_bounds__(NT, 4) void reservoir_kernel(
    const float* __restrict__ inputs, const float* __restrict__ state0,
    const float* __restrict__ kvals,  const float* __restrict__ rvals,
    const float* __restrict__ bias,   const int* __restrict__ krows,
    const int* __restrict__ kcols,    const int* __restrict__ ridx,
    const int* __restrict__ offA,     const float* __restrict__ wA,
    const int* __restrict__ offB,     const float* __restrict__ wB,
    float* __restrict__ out)
{
  __shared__ __align__(16) char smem[LDS_BYTES];
  const int tid = threadIdx.x;
  const int b   = blockIdx.x;
  const int u0  = tid * 2;

  // copy-B publish address: pair {v(u0), v(u0)^1} is b64-aligned, possibly
  // element-swapped (v(u0) odd)
  const int  v0    = u0 ^ ((u0 >> 5) & 31);
  const int  vbyte = 8192 + (v0 & ~1) * 4;
  const bool vswap = (v0 & 1) != 0;

  *(f32x2*)(smem + IA + tid * 8) = (f32x2){0.f, 0.f};
  *(f32x2*)(smem + IB + tid * 8) = (f32x2){0.f, 0.f};

  f32x2 h0 = *(const f32x2*)(state0 + b * UNITS + u0);
  *(f32x2*)(smem + HPING + tid * 8) = h0;
  f32x2 h0b = vswap ? (f32x2){h0.y, h0.x} : h0;
  *(f32x2*)(smem + HPING + vbyte) = h0b;

  RDECL(0) RDECL(1) RDECL(2) RDECL(3) RDECL(4)
  RDECL(5) RDECL(6) RDECL(7) RDECL(8) RDECL(9)

  const f32x2 bias2 = *(const f32x2*)(bias + u0);

  int krb = 0, kcb = 0; float kv = 0.f;
  if (tid < NNZ) {
    krb = krows[tid] * 4;
    kcb = kcols[tid] * 4;
    kv  = kvals[tid];
  }

  const float* xin  = inputs + (size_t)b * (T * D_IN);
  f32x2*       outp = (f32x2*)out + (size_t)b * (T * (UNITS / 2)) + tid;

  __syncthreads();

  for (int tb = 0; tb < T; tb += CHUNK) {
#pragma unroll
    for (int k = 0; k < 3; ++k) {
      float4 v = *(const float4*)(xin + tb * D_IN + (tid + k * NT) * 4);
      *(float4*)(smem + XO + (tid + k * NT) * 16) = v;
    }
    bar_lds();
    if (tid < NNZ) {
      float xv = *(const float*)(smem + XO + krb);
      atomicAdd((float*)(smem + IA + kcb), xv * kv);
    }
    bar_lds();
#pragma unroll 1
    for (int ts = 0; ts < CHUNK; ts += 2) {
      STEP(HPING, HPONG, IA, IB, ts + 1, true,              tb + ts);
      STEP(HPONG, HPING, IB, IA, ts + 2, (ts + 2) < CHUNK,  tb + ts + 1);
    }
  }
}

extern "C" void kernel_launch(void* const* d_in, const int* in_sizes, int n_in,
                              void* d_out, int out_size, void* d_ws, size_t ws_size,
                              hipStream_t stream) {
  const float* inputs = (const float*)d_in[0];
  const float* state0 = (const float*)d_in[1];
  const float* kvals  = (const float*)d_in[2];
  const float* rvals  = (const float*)d_in[3];
  const float* bias   = (const float*)d_in[4];
  const int*   krows  = (const int*)d_in[5];
  const int*   kcols  = (const int*)d_in[6];
  const int*   ridx   = (const int*)d_in[7];

  int*   offA = (int*)((char*)d_ws + OFFA_OFS);
  float* wA   = (float*)((char*)d_ws + WA_OFS);
  int*   offB = (int*)((char*)d_ws + OFFB_OFS);
  float* wB   = (float*)((char*)d_ws + WB_OFS);

  if (ws_size >= (size_t)WS_NEED) {
    prep_kernel<<<dim3(1), dim3(1024), 0, stream>>>(ridx, rvals, offA, wA, offB, wB);
    reservoir_kernel<true><<<dim3(BATCH), dim3(NT), 0, stream>>>(
        inputs, state0, kvals, rvals, bias, krows, kcols, ridx,
        offA, wA, offB, wB, (float*)d_out);
  } else {
    reservoir_kernel<false><<<dim3(BATCH), dim3(NT), 0, stream>>>(
        inputs, state0, kvals, rvals, bias, krows, kcols, ridx,
        offA, wA, offB, wB, (float*)d_out);
  }
}